// Round 5
// baseline (190.289 us; speedup 1.0000x reference)
//
#include <hip/hip_runtime.h>
#include <hip/hip_bf16.h>
#include <math.h>

// Problem constants (fixed by setup_inputs)
#define B_  2
#define NH  4
#define HH  64
#define WW  64
#define KD  32
#define L_  4096            // HH*WW
#define BN_ 8               // B_*NH
#define SCALE 0.17677669529663687f       // 1/sqrt(32)
#define LOG2E 1.4426950408889634f
#define KSCALE (0.17677669529663687f * 1.4426950408889634f)  // fold log2e into K
#define MARGIN 4.0f                      // log2-domain margin: p <= 16

// MFMA fragment types (guide §3: 8 bf16 in 4 VGPRs, 4 fp32 acc)
typedef short bfrag  __attribute__((ext_vector_type(8), may_alias));
typedef float f32x4  __attribute__((ext_vector_type(4), may_alias));

__device__ __forceinline__ unsigned short f2bf(float f) {
    __hip_bfloat16 h = __float2bfloat16(f);
    return *(unsigned short*)&h;
}

__device__ __forceinline__ float fexp2(float x) {
#if __has_builtin(__builtin_amdgcn_exp2f)
    return __builtin_amdgcn_exp2f(x);
#else
    return __expf(x * 0.69314718056f);
#endif
}

// ---------------------------------------------------------------------------
// Kernel A: qkv = x @ w_qkv  (M=8192, K=128, N=384).
// Outputs: q_f32 [bn][l][32] (for bias tables), q_bf/k_bf [bn][l][32] bf16
// (k pre-scaled by log2e/sqrt(32)), vt_bf [bn][32][l] bf16 (V transposed).
// ---------------------------------------------------------------------------
__global__ __launch_bounds__(256) void qkv_gemm(const float* __restrict__ x,
                                                const float* __restrict__ w,
                                                float* __restrict__ q_f32,
                                                unsigned short* __restrict__ q_bf,
                                                unsigned short* __restrict__ k_bf,
                                                unsigned short* __restrict__ vt_bf) {
    __shared__ float As[64][68];
    __shared__ float Bs[64][68];
    const int mt = blockIdx.x % 128;
    const int nt = blockIdx.x / 128;
    const int m0 = mt * 64, n0 = nt * 64;
    const int tid = threadIdx.x;
    const int ti = tid / 16, tj = tid % 16;
    float acc[4][4] = {};

    for (int k0 = 0; k0 < 128; k0 += 64) {
        #pragma unroll
        for (int i = 0; i < 16; i++) {
            int e = i * 256 + tid;
            int row = e >> 6, col = e & 63;
            As[row][col] = x[(m0 + row) * 128 + k0 + col];
        }
        #pragma unroll
        for (int i = 0; i < 16; i++) {
            int e = i * 256 + tid;
            int kk = e >> 6, col = e & 63;
            Bs[kk][col] = w[(k0 + kk) * 384 + n0 + col];
        }
        __syncthreads();
        #pragma unroll 8
        for (int kk = 0; kk < 64; kk++) {
            float av[4];
            #pragma unroll
            for (int r = 0; r < 4; r++) av[r] = As[ti * 4 + r][kk];
            const float4 b4 = *(const float4*)&Bs[kk][tj * 4];
            const float bv[4] = {b4.x, b4.y, b4.z, b4.w};
            #pragma unroll
            for (int r = 0; r < 4; r++)
                #pragma unroll
                for (int c = 0; c < 4; c++)
                    acc[r][c] = fmaf(av[r], bv[c], acc[r][c]);
        }
        __syncthreads();
    }

    const int which = n0 >> 7;                 // 0=q, 1=k, 2=v
    const int nc = n0 & 127;
    #pragma unroll
    for (int r = 0; r < 4; r++) {
        const int m = m0 + ti * 4 + r;
        const int b = m >> 12, l = m & 4095;
        #pragma unroll
        for (int c = 0; c < 4; c++) {
            const int col = nc + tj * 4 + c;
            const int hd = col >> 5, d = col & 31;
            const int bn = b * NH + hd;
            const float v = acc[r][c];
            if (which == 0) {
                q_f32[((size_t)bn * L_ + l) * 32 + d] = v;
                q_bf [((size_t)bn * L_ + l) * 32 + d] = f2bf(v);
            } else if (which == 1) {
                k_bf [((size_t)bn * L_ + l) * 32 + d] = f2bf(v * KSCALE);
            } else {
                vt_bf[((size_t)bn * 32 + d) * L_ + l] = f2bf(v);
            }
        }
    }
}

// ---------------------------------------------------------------------------
// Kernel B: absolute-indexed relative bias tables, in log2 domain (x LOG2E).
//   qw_abs[bn][w2][w1][h1] = log2e * dot(q[bn,h1,w1,:], emb_w[w2-w1+63,:])
//   qh_abs[bn][h2][w1][h1] = log2e * dot(q[bn,h1,w1,:], emb_h[m2-h1+63,:])
// Eh stored transposed+float2-interleaved in LDS -> lane-consecutive reads,
// conflict-free. Ew row is wave-uniform -> s_load path via readfirstlane.
// q row held in 32 registers.
// ---------------------------------------------------------------------------
__global__ __launch_bounds__(256) void bias_tables(const float* __restrict__ q_f32,
                                                   const float* __restrict__ emb_h,
                                                   const float* __restrict__ emb_w,
                                                   float* __restrict__ qw_abs,
                                                   float* __restrict__ qh_abs) {
    __shared__ float qs[64][36];
    __shared__ float2 eh2[16][128];    // [d/2][j], interleaved pairs (16 KB)
    const int bn = blockIdx.x >> 6;
    const int w1 = blockIdx.x & 63;
    const int tid = threadIdx.x;

    #pragma unroll
    for (int i = 0; i < 8; i++) {
        int e = i * 256 + tid;
        qs[e >> 5][e & 31] = q_f32[((size_t)bn * L_ + (e >> 5) * 64 + w1) * 32 + (e & 31)];
    }
    #pragma unroll
    for (int i = 0; i < 8; i++) {       // 2048 slots = 16 dpair x 128 j
        int e = i * 256 + tid;
        int dp = e >> 7, j = e & 127;
        float a = 0.f, b = 0.f;
        if (j < 127) { a = emb_h[j * 32 + dp * 2]; b = emb_h[j * 32 + dp * 2 + 1]; }
        eh2[dp][j] = make_float2(a, b);
    }
    __syncthreads();

    const int h1 = tid & 63;
    const int mg = tid >> 6;
    float qreg[32];
    #pragma unroll
    for (int j = 0; j < 8; j++) {
        const float4 t = *(const float4*)&qs[h1][j * 4];
        qreg[j * 4 + 0] = t.x; qreg[j * 4 + 1] = t.y;
        qreg[j * 4 + 2] = t.z; qreg[j * 4 + 3] = t.w;
    }
    for (int mm = 0; mm < 16; mm++) {
        const int m2 = mg * 16 + mm;
        const int jw = __builtin_amdgcn_readfirstlane(m2 - w1 + 63);   // uniform
        const float* __restrict__ ewrow = emb_w + jw * 32;
        const int jh = m2 - h1 + 63;                                   // 0..126
        float sw0 = 0.f, sw1 = 0.f, sh0 = 0.f, sh1 = 0.f;
        #pragma unroll
        for (int dp = 0; dp < 16; dp++) {
            const float2 eh = eh2[dp][jh];
            sh0 = fmaf(qreg[dp * 2],     eh.x, sh0);
            sh1 = fmaf(qreg[dp * 2 + 1], eh.y, sh1);
            sw0 = fmaf(qreg[dp * 2],     ewrow[dp * 2],     sw0);
            sw1 = fmaf(qreg[dp * 2 + 1], ewrow[dp * 2 + 1], sw1);
        }
        const size_t oidx = (size_t)bn * (64 * L_) + (size_t)m2 * L_ + w1 * 64 + h1;
        qw_abs[oidx] = (sw0 + sw1) * LOG2E;
        qh_abs[oidx] = (sh0 + sh1) * LOG2E;
    }
}

// ---------------------------------------------------------------------------
// Kernel C: MFMA flash attention, PV software-pipelined by one tile.
// Grid 1024 = (bn, w1, q-half). Block 512 thr = 8 waves = 2 q-waves x 4 key
// splits (16 tiles of 64 keys each). All scores in log2 domain (K and bias
// pre-scaled by log2e) -> raw v_exp2. qh bias folded into softmax via
// mq = m - qh (no C-init add). Iter t: read P(t-1) -> QK(t) -> PV(t-1) ->
// vote/rescale -> exp2/write P(t). LDS 18.4 KB: per-wave P buffers, reused
// for the 4-way split merge after a barrier.
// ---------------------------------------------------------------------------
__global__ __launch_bounds__(512) void attn_mfma(
    const unsigned short* __restrict__ q_bf,   // [bn][l][32]
    const unsigned short* __restrict__ k_bf,   // [bn][l][32], pre-scaled
    const unsigned short* __restrict__ vt_bf,  // [bn][32][l]
    const float* __restrict__ qw_abs,          // [bn][w2][w1][h1], log2 dom
    const float* __restrict__ qh_abs,          // [bn][h2][w1][h1], log2 dom
    float* __restrict__ out)
{
    __shared__ __align__(16) char smem[18432];  // 8 x 2304B P | merge buffers

    const int bi   = blockIdx.x;
    const int bn   = bi >> 7;
    const int w1   = (bi >> 1) & 63;
    const int qhf  = bi & 1;
    const int tid  = threadIdx.x;
    const int wv   = tid >> 6;
    const int sp   = wv >> 1;            // key split 0..3
    const int qwv  = wv & 1;             // query wave 0/1
    const int lane = tid & 63;
    const int l16  = lane & 15;
    const int quad = lane >> 4;
    const int q0   = qhf * 32 + qwv * 16;

    unsigned short* Pw = (unsigned short*)(smem + wv * 2304);

    // ---- Q A-frag: lane holds Q[q0+l16][quad*8..+8) ----
    const bfrag aq = *(const bfrag*)(q_bf +
        (((size_t)bn * L_ + (q0 + l16) * 64 + w1) * 32 + quad * 8));

    // ---- loop-invariant qw bias (C-init): [w2=sub*16+l16][q0+quad*4..+4) ----
    f32x4 qwreg[4];
    #pragma unroll
    for (int sub = 0; sub < 4; sub++)
        qwreg[sub] = *(const f32x4*)&qw_abs[((size_t)bn * 64 + sub * 16 + l16) * L_
                                            + w1 * 64 + q0 + quad * 4];

    const unsigned short* Kbase = k_bf  + (size_t)bn * L_ * 32;
    const unsigned short* Vbase = vt_bf + (size_t)bn * 32 * L_;
    const float* qh_base = qh_abs + (size_t)bn * 64 * L_ + w1 * 64 + q0 + quad * 4;

    const int kt0 = sp * 16, ktend = kt0 + 16;

    // ---- K prefetch-held; qh double-var ----
    bfrag kf[4];
    #pragma unroll
    for (int sub = 0; sub < 4; sub++)
        kf[sub] = *(const bfrag*)(Kbase + (size_t)(kt0 * 64 + sub * 16 + l16) * 32 + quad * 8);
    f32x4 qh4 = *(const f32x4*)&qh_base[(size_t)kt0 * L_];

    f32x4 O0 = {0.f, 0.f, 0.f, 0.f}, O1 = {0.f, 0.f, 0.f, 0.f};
    float m_[4], l_[4];
    #pragma unroll
    for (int r = 0; r < 4; r++) { m_[r] = -INFINITY; l_[r] = 0.f; }

    // iter kt: QK+softmax+writeP for tile kt (kt<ktend), PV for tile kt-1.
    for (int kt = kt0; kt <= ktend; kt++) {
        const bool doQK = (kt < ktend);
        const bool doPV = (kt > kt0);

        bfrag pa0, pa1, vfa0, vfa1, vfa2, vfa3;
        if (doPV) {                              // issue early: slack = QK+softmax
            pa0 = *(const bfrag*)(Pw + l16 * 72 + quad * 8);
            pa1 = *(const bfrag*)(Pw + l16 * 72 + 32 + quad * 8);
            const int vt = kt - 1;
            vfa0 = *(const bfrag*)(Vbase + (size_t)l16 * L_        + vt * 64      + quad * 8);
            vfa1 = *(const bfrag*)(Vbase + (size_t)l16 * L_        + vt * 64 + 32 + quad * 8);
            vfa2 = *(const bfrag*)(Vbase + (size_t)(16 + l16) * L_ + vt * 64      + quad * 8);
            vfa3 = *(const bfrag*)(Vbase + (size_t)(16 + l16) * L_ + vt * 64 + 32 + quad * 8);
        }

        f32x4 S[4];
        float mx[4], mq[4];
        f32x4 qh4n = qh4;
        if (doQK) {
            #pragma unroll
            for (int sub = 0; sub < 4; sub++)
                S[sub] = __builtin_amdgcn_mfma_f32_16x16x32_bf16(aq, kf[sub],
                                                                 qwreg[sub], 0, 0, 0);
            // prefetch K + qh for next tile (full-iter slack)
            const int ktn = (kt + 1 < ktend) ? kt + 1 : kt;
            #pragma unroll
            for (int sub = 0; sub < 4; sub++)
                kf[sub] = *(const bfrag*)(Kbase + (size_t)(ktn * 64 + sub * 16 + l16) * 32 + quad * 8);
            qh4n = *(const f32x4*)&qh_base[(size_t)ktn * L_];
            #pragma unroll
            for (int r = 0; r < 4; r++)
                mx[r] = fmaxf(fmaxf(S[0][r], S[1][r]), fmaxf(S[2][r], S[3][r]));
        }

        if (doPV) {                              // uses pre-rescale O (old m) ✓
            O0 = __builtin_amdgcn_mfma_f32_16x16x32_bf16(pa0, vfa0, O0, 0, 0, 0);
            O0 = __builtin_amdgcn_mfma_f32_16x16x32_bf16(pa1, vfa1, O0, 0, 0, 0);
            O1 = __builtin_amdgcn_mfma_f32_16x16x32_bf16(pa0, vfa2, O1, 0, 0, 0);
            O1 = __builtin_amdgcn_mfma_f32_16x16x32_bf16(pa1, vfa3, O1, 0, 0, 0);
        }

        if (doQK) {
            // vote-gated rescale: true row max = redmax(mx) + qh; margin'd
            const int need = (mx[0] > m_[0] - qh4[0]) | (mx[1] > m_[1] - qh4[1]) |
                             (mx[2] > m_[2] - qh4[2]) | (mx[3] > m_[3] - qh4[3]);
            if (__any(need)) {
                #pragma unroll
                for (int r = 0; r < 4; r++) {
                    float v = mx[r];
                    #pragma unroll
                    for (int st = 1; st < 16; st <<= 1)
                        v = fmaxf(v, __shfl_xor(v, st));
                    const float mn = fmaxf(m_[r], v + qh4[r] + MARGIN);
                    const float al = fexp2(m_[r] - mn);   // 2^(-inf)=0 first time
                    m_[r] = mn;
                    l_[r] *= al;
                    O0[r] *= al;
                    O1[r] *= al;
                }
            }
            #pragma unroll
            for (int r = 0; r < 4; r++) mq[r] = m_[r] - qh4[r];
            #pragma unroll
            for (int sub = 0; sub < 4; sub++)
                #pragma unroll
                for (int r = 0; r < 4; r++) {
                    const float p = fexp2(S[sub][r] - mq[r]);
                    l_[r] += p;
                    Pw[(quad * 4 + r) * 72 + sub * 16 + l16] = f2bf(p);
                }
            qh4 = qh4n;
        }
    }

    // ---- reduce l across the 16 lanes of each row ----
    #pragma unroll
    for (int st = 1; st < 16; st <<= 1)
        #pragma unroll
        for (int r = 0; r < 4; r++)
            l_[r] += __shfl_xor(l_[r], st);

    // ---- 4-way split merge; reuse P region (all waves past their P reads) ----
    float* mO = (float*)smem;                    // [3][2][16][34]
    float* mM = (float*)(smem + 13056);          // [3][2][16]
    float* mL = (float*)(smem + 13440);          // [3][2][16]
    __syncthreads();
    if (sp > 0) {
        #pragma unroll
        for (int r = 0; r < 4; r++) {
            const int q16 = quad * 4 + r;
            const int gi = ((sp - 1) * 2 + qwv) * 16 + q16;
            mO[gi * 34 + l16]      = O0[r];
            mO[gi * 34 + 16 + l16] = O1[r];
            if (l16 == 0) { mM[gi] = m_[r]; mL[gi] = l_[r]; }
        }
    }
    __syncthreads();
    if (sp == 0) {
        const int head = bn & 3, bb = bn >> 2;
        #pragma unroll
        for (int r = 0; r < 4; r++) {
            const int q16 = quad * 4 + r;
            float M = m_[r];
            #pragma unroll
            for (int s = 0; s < 3; s++)
                M = fmaxf(M, mM[(s * 2 + qwv) * 16 + q16]);
            const float e0 = fexp2(m_[r] - M);
            float denom = e0 * l_[r];
            float o0 = e0 * O0[r], o1 = e0 * O1[r];
            #pragma unroll
            for (int s = 0; s < 3; s++) {
                const int gi = (s * 2 + qwv) * 16 + q16;
                const float es = fexp2(mM[gi] - M);
                denom += es * mL[gi];
                o0 += es * mO[gi * 34 + l16];
                o1 += es * mO[gi * 34 + 16 + l16];
            }
            const float inv = 1.0f / denom;
            const int q = q0 + q16;
            const size_t oi = (((size_t)bb * 64 + q) * 64 + w1) * 128 + head * 32;
            out[oi + l16]      = o0 * inv;
            out[oi + 16 + l16] = o1 * inv;
        }
    }
}

// ---------------------------------------------------------------------------
extern "C" void kernel_launch(void* const* d_in, const int* in_sizes, int n_in,
                              void* d_out, int out_size, void* d_ws, size_t ws_size,
                              hipStream_t stream) {
    const float* x     = (const float*)d_in[0];   // [2,64,64,128]
    const float* w_qkv = (const float*)d_in[1];   // [128,384]
    const float* emb_h = (const float*)d_in[2];   // [127,32]
    const float* emb_w = (const float*)d_in[3];   // [127,32]
    float* out = (float*)d_out;

    // workspace: q_f32 (1M f), qw_abs (2M f), qh_abs (2M f), then bf16:
    // q_bf, k_bf, vt_bf (1M ush each) -> 26 MB total
    float* q_f32  = (float*)d_ws;
    float* qw_abs = q_f32 + (size_t)BN_ * L_ * KD;
    float* qh_abs = qw_abs + (size_t)BN_ * 64 * L_;
    unsigned short* q_bf  = (unsigned short*)(qh_abs + (size_t)BN_ * 64 * L_);
    unsigned short* k_bf  = q_bf + (size_t)BN_ * L_ * KD;
    unsigned short* vt_bf = k_bf + (size_t)BN_ * L_ * KD;

    qkv_gemm<<<768, 256, 0, stream>>>(x, w_qkv, q_f32, q_bf, k_bf, vt_bf);
    bias_tables<<<512, 256, 0, stream>>>(q_f32, emb_h, emb_w, qw_abs, qh_abs);
    attn_mfma<<<1024, 512, 0, stream>>>(q_bf, k_bf, vt_bf, qw_abs, qh_abs, out);
}